// Round 9
// baseline (45.101 us; speedup 1.0000x reference)
//
#include <hip/hip_runtime.h>

// YOLO loss: S=28, B=2, NUM_CLASSES=20, L_COORD=5, L_NOOBJ=0.5, N=1024
// Inputs (fp32 unless noted):
//   d_in[0] pred_tensor  (N,28,28,30)
//   d_in[1] target_boxes (N,28,28,4)
//   d_in[2] target_cls   (N,28,28,20)
//   d_in[3] has_object_map (N,28,28) bool -> int32 on device
// Output: 5 floats [total, reg, contain, noobj, cls]
//
// R9: two-phase LDS-reuse staging. Constraint discovered: full staging
// (R6, 120B/thread LDS) hard-caps occupancy at 20 waves/CU; staging less
// + scattered global cls reads (R7/R8) loses more than occupancy gains.
// This keeps ALL reads coalesced-or-LDS while peak LDS = 80B/cell:
//   phase A: stage words 0..9 -> noobj + IoU/reg/contain
//   phase B: restage words 10..29 into the SAME buffer -> cls loss
// stride 22 floats (8B-aligned, gcd(22,32)=2 -> free 2-way) = 22.5KB
// -> 7 blocks/CU = 28 waves (vs R6's 20).
// Ladder: R2 35.5 / R6 31.2 (best) / R7 35.5 / R8 34.9 (both confounded).

__device__ inline float wave_reduce(float v) {
    #pragma unroll
    for (int off = 32; off > 0; off >>= 1)
        v += __shfl_down(v, off, 64);
    return v;
}

__global__ void __launch_bounds__(256) yolo_partial(
    const float* __restrict__ pred,
    const float* __restrict__ tbox,
    const float* __restrict__ tcls,
    const int*  __restrict__ mask,
    float* __restrict__ partial, int ncells)
{
    __shared__ float sb[256 * 22];          // 22528 B, reused A->B
    const float inv_s = 1.0f / 28.0f;

    const int base = blockIdx.x * 256;
    const int nc   = min(256, ncells - base);
    const float2* g2 = (const float2*)pred + (size_t)base * 15;

    // ================= PHASE A: box+conf (words 0..9) =================
    if (nc == 256) {
        #pragma unroll
        for (int i = 0; i < 5; ++i) {
            int j = threadIdx.x + i * 256;      // 0..1279
            int cell = j / 5;                   // magic-mul
            int off  = j - cell * 5;            // float2 idx 0..4
            float2 v = g2[cell * 15 + off];
            sb[cell * 22 + 2*off]     = v.x;
            sb[cell * 22 + 2*off + 1] = v.y;
        }
    } else {
        for (int w = threadIdx.x; w < nc * 10; w += 256) {
            int i = w / 10, k = w - i * 10;
            sb[i * 22 + k] = pred[(size_t)(base + i) * 30 + k];
        }
    }
    __syncthreads();

    float s_cls = 0.f, s_noobj = 0.f, s_contain = 0.f, s_reg = 0.f;
    bool is_obj = false;

    const int cell = base + threadIdx.x;
    if (threadIdx.x < nc) {
        const float* w = sb + threadIdx.x * 22; // [x0,y0,w0,h0,c0, x1,y1,w1,h1,c1]
        float conf0 = w[4], conf1 = w[9];
        is_obj = (mask[cell] != 0);

        if (!is_obj) {
            s_noobj = conf0*conf0 + conf1*conf1;   // x0.5 at the end
        } else {
            // target box -> xyxy
            float4 tb = ((const float4*)tbox)[cell];
            float tx = tb.x * inv_s, ty = tb.y * inv_s;
            float tx1 = tx - 0.5f*tb.z, ty1 = ty - 0.5f*tb.w;
            float tx2 = tx + 0.5f*tb.z, ty2 = ty + 0.5f*tb.w;
            float area_t = (tx2 - tx1) * (ty2 - ty1);

            float bxv[2] = {w[0], w[5]}, byv[2] = {w[1], w[6]};
            float bwv[2] = {w[2], w[7]}, bhv[2] = {w[3], w[8]};
            float confv[2] = {conf0, conf1};
            float iou[2];
            #pragma unroll
            for (int b = 0; b < 2; b++) {
                float px = bxv[b] * inv_s, py = byv[b] * inv_s;
                float px1 = px - 0.5f*bwv[b], py1 = py - 0.5f*bhv[b];
                float px2 = px + 0.5f*bwv[b], py2 = py + 0.5f*bhv[b];
                float ltx = fmaxf(px1, tx1), lty = fmaxf(py1, ty1);
                float rbx = fminf(px2, tx2), rby = fminf(py2, ty2);
                float ww = fmaxf(rbx - ltx, 0.f), hh = fmaxf(rby - lty, 0.f);
                float inter = ww * hh;
                float area_p = (px2 - px1) * (py2 - py1);
                iou[b] = inter / (area_p + area_t - inter);
            }
            int bi = (iou[1] > iou[0]) ? 1 : 0;   // argmax: first on ties
            float biou = fmaxf(iou[0], iou[1]);

            float bbx = bxv[bi], bby = byv[bi], bbw = bwv[bi], bbh = bhv[bi], bconf = confv[bi];

            // regression loss (x5 at the end)
            float dx = bbx - tb.x, dy = bby - tb.y;
            float center = dx*dx + dy*dy;
            float sw = sqrtf(fmaxf(bbw, 0.f)) - sqrtf(tb.z);
            float sh = sqrtf(fmaxf(bbh, 0.f)) - sqrtf(tb.w);
            s_reg = center + sw*sw + sh*sh;

            // containment loss
            float dc = bconf - biou;
            s_contain = dc * dc;
        }
    }

    // ================= PHASE B: cls (words 10..29) =================
    __syncthreads();                        // phase-A reads done before overwrite
    if (nc == 256) {
        #pragma unroll
        for (int i = 0; i < 10; ++i) {
            int j = threadIdx.x + i * 256;      // 0..2559
            int cell2 = j / 10;                 // magic-mul
            int off  = j - cell2 * 10;          // float2 idx 0..9 (=5..14 of cell)
            float2 v = g2[cell2 * 15 + 5 + off];
            sb[cell2 * 22 + 2*off]     = v.x;
            sb[cell2 * 22 + 2*off + 1] = v.y;
        }
    } else {
        for (int w = threadIdx.x; w < nc * 20; w += 256) {
            int i = w / 20, k = w - i * 20;
            sb[i * 22 + k] = pred[(size_t)(base + i) * 30 + 10 + k];
        }
    }
    __syncthreads();

    if (is_obj) {
        const float2* pc2 = (const float2*)(sb + threadIdx.x * 22);
        const float4* c4 = (const float4*)tcls + (size_t)cell * 5;
        float cl = 0.f;
        #pragma unroll
        for (int k = 0; k < 5; k++) {
            float4 t = c4[k];
            float2 a = pc2[2*k], b = pc2[2*k+1];
            float d0 = a.x - t.x, d1 = a.y - t.y;
            float d2 = b.x - t.z, d3 = b.y - t.w;
            cl += d0*d0 + d1*d1 + d2*d2 + d3*d3;
        }
        s_cls = cl;
    }

    // ---- block reduce: 4 waves x 4 sums
    __shared__ float red[4][4];
    int lane = threadIdx.x & 63, wid = threadIdx.x >> 6;
    s_cls = wave_reduce(s_cls);
    s_noobj = wave_reduce(s_noobj);
    s_contain = wave_reduce(s_contain);
    s_reg = wave_reduce(s_reg);
    if (lane == 0) {
        red[wid][0] = s_cls; red[wid][1] = s_noobj;
        red[wid][2] = s_contain; red[wid][3] = s_reg;
    }
    __syncthreads();
    if (threadIdx.x < 4) {
        float acc = red[0][threadIdx.x] + red[1][threadIdx.x]
                  + red[2][threadIdx.x] + red[3][threadIdx.x];
        partial[(size_t)blockIdx.x * 4 + threadIdx.x] = acc;
    }
}

__global__ void __launch_bounds__(256) yolo_final(
    const float* __restrict__ partial, int nblocks, float* __restrict__ out)
{
    float s0 = 0.f, s1 = 0.f, s2 = 0.f, s3 = 0.f;
    const float4* p4 = (const float4*)partial;
    for (int i = threadIdx.x; i < nblocks; i += 256) {
        float4 t = p4[i];
        s0 += t.x; s1 += t.y; s2 += t.z; s3 += t.w;
    }
    __shared__ float red[4][4];
    int lane = threadIdx.x & 63, wid = threadIdx.x >> 6;
    s0 = wave_reduce(s0); s1 = wave_reduce(s1);
    s2 = wave_reduce(s2); s3 = wave_reduce(s3);
    if (lane == 0) { red[wid][0]=s0; red[wid][1]=s1; red[wid][2]=s2; red[wid][3]=s3; }
    __syncthreads();
    if (threadIdx.x == 0) {
        float cls = 0.f, noobj = 0.f, contain = 0.f, reg = 0.f;
        #pragma unroll
        for (int w = 0; w < 4; w++) {
            cls += red[w][0]; noobj += red[w][1];
            contain += red[w][2]; reg += red[w][3];
        }
        noobj *= 0.5f;   // L_NOOBJ
        reg   *= 5.0f;   // L_COORD
        float total = (cls + noobj + contain + reg) / 1024.0f;
        out[0] = total; out[1] = reg; out[2] = contain;
        out[3] = noobj; out[4] = cls;
    }
}

extern "C" void kernel_launch(void* const* d_in, const int* in_sizes, int n_in,
                              void* d_out, int out_size, void* d_ws, size_t ws_size,
                              hipStream_t stream) {
    const float* pred = (const float*)d_in[0];
    const float* tbox = (const float*)d_in[1];
    const float* tcls = (const float*)d_in[2];
    const int*   mask = (const int*)d_in[3];

    int ncells = in_sizes[3];                 // N * S * S = 802816
    int nblocks = (ncells + 255) / 256;       // 3136
    int maxblocks = (int)(ws_size / (4 * sizeof(float)));
    if (nblocks > maxblocks) nblocks = maxblocks;
    if (nblocks < 1) nblocks = 1;

    yolo_partial<<<nblocks, 256, 0, stream>>>(
        pred, tbox, tcls, mask, (float*)d_ws, ncells);
    yolo_final<<<1, 256, 0, stream>>>((float*)d_ws, nblocks, (float*)d_out);
}

// Round 10
// 31.093 us; speedup vs baseline: 1.4505x; 1.4505x over previous
//
#include <hip/hip_runtime.h>

// YOLO loss: S=28, B=2, NUM_CLASSES=20, L_COORD=5, L_NOOBJ=0.5, N=1024
// Inputs (fp32 unless noted):
//   d_in[0] pred_tensor  (N,28,28,30)
//   d_in[1] target_boxes (N,28,28,4)
//   d_in[2] target_cls   (N,28,28,20)
//   d_in[3] has_object_map (N,28,28) bool -> int32 on device
// Output: 5 floats [total, reg, contain, noobj, cls]
//
// R10 = R6 (best, 31.2us) with ONE change: staging uses
// __builtin_amdgcn_global_load_lds(width=16) HBM->LDS DMA instead of
// global->VGPR->LDS (halves staging issue slots, drops VGPR round trip).
// LDS dest is linear in lane order (idx*16) = the required wave-uniform
// base + lane*16 pattern; i=0..6 are full waves, 128-float4 tail via
// plain path. __syncthreads() drains vmcnt before LDS reads (m97 pattern).
// Ladder: R2 35.5 / R6 31.2 / R7 35.5 / R8 34.9 / R9 45.1 (occupancy
// arc dead: staging coalescing + single pass dominates).

__device__ inline float wave_reduce(float v) {
    #pragma unroll
    for (int off = 32; off > 0; off >>= 1)
        v += __shfl_down(v, off, 64);
    return v;
}

__global__ void __launch_bounds__(256) yolo_partial(
    const float* __restrict__ pred,
    const float* __restrict__ tbox,
    const float* __restrict__ tcls,
    const int*  __restrict__ mask,
    float* __restrict__ partial, int ncells)
{
    __shared__ float sp[7680];              // 256 cells x 30 floats = 30720 B
    const float inv_s = 1.0f / 28.0f;

    const int base = blockIdx.x * 256;
    const int nc   = min(256, ncells - base);

    // ---- stage pred chunk into LDS ----
    if (nc == 256) {
        const float4* g4 = (const float4*)pred + (size_t)blockIdx.x * 1920;
        float4* s4 = (float4*)sp;
        #pragma unroll
        for (int i = 0; i < 7; ++i) {
            int idx = threadIdx.x + i * 256;    // 0..1791, full waves
            __builtin_amdgcn_global_load_lds(
                (const __attribute__((address_space(1))) uint32_t*)(g4 + idx),
                (__attribute__((address_space(3))) uint32_t*)(s4 + idx),
                16, 0, 0);
        }
        if (threadIdx.x < 128) {                // tail float4s 1792..1919
            int idx = 1792 + threadIdx.x;
            s4[idx] = g4[idx];
        }
    } else {
        for (int w = threadIdx.x; w < nc * 30; w += 256)
            sp[w] = pred[(size_t)base * 30 + w];
    }
    __syncthreads();    // drains vmcnt(0) + lgkmcnt(0) before LDS reads

    float s_cls = 0.f, s_noobj = 0.f, s_contain = 0.f, s_reg = 0.f;

    const int cell = base + threadIdx.x;
    if (threadIdx.x < nc) {
        const float2* p2 = (const float2*)(sp + threadIdx.x * 30);
        // conf words needed on BOTH paths
        float2 v2 = p2[2], v4 = p2[4];
        float conf0 = v2.x, conf1 = v4.y;

        if (mask[cell] == 0) {
            // ---- no-object path (75% of lanes): conf only
            s_noobj = conf0*conf0 + conf1*conf1;   // x0.5 at the end
        } else {
            // ---- object path (25% of lanes): everything else, m == 1
            float2 v0 = p2[0], v1 = p2[1], v3 = p2[3];
            // box0 = (v0.x, v0.y, v1.x, v1.y, conf0)
            // box1 = (v2.y, v3.x, v3.y, v4.x, conf1)

            // class loss
            float pc[20];
            #pragma unroll
            for (int k = 0; k < 10; k++) { float2 t = p2[5 + k]; pc[2*k] = t.x; pc[2*k+1] = t.y; }
            const float4* c4 = (const float4*)tcls + (size_t)cell * 5;
            float cl = 0.f;
            #pragma unroll
            for (int k = 0; k < 5; k++) {
                float4 t = c4[k];
                float d0 = pc[4*k+0] - t.x, d1 = pc[4*k+1] - t.y;
                float d2 = pc[4*k+2] - t.z, d3 = pc[4*k+3] - t.w;
                cl += d0*d0 + d1*d1 + d2*d2 + d3*d3;
            }
            s_cls = cl;

            // target box -> xyxy
            float4 tb = ((const float4*)tbox)[cell];
            float tx = tb.x * inv_s, ty = tb.y * inv_s;
            float tx1 = tx - 0.5f*tb.z, ty1 = ty - 0.5f*tb.w;
            float tx2 = tx + 0.5f*tb.z, ty2 = ty + 0.5f*tb.w;
            float area_t = (tx2 - tx1) * (ty2 - ty1);

            // IoU of both pred boxes vs target
            float bxv[2] = {v0.x, v2.y}, byv[2] = {v0.y, v3.x};
            float bwv[2] = {v1.x, v3.y}, bhv[2] = {v1.y, v4.x};
            float confv[2] = {conf0, conf1};
            float iou[2];
            #pragma unroll
            for (int b = 0; b < 2; b++) {
                float px = bxv[b] * inv_s, py = byv[b] * inv_s;
                float px1 = px - 0.5f*bwv[b], py1 = py - 0.5f*bhv[b];
                float px2 = px + 0.5f*bwv[b], py2 = py + 0.5f*bhv[b];
                float ltx = fmaxf(px1, tx1), lty = fmaxf(py1, ty1);
                float rbx = fminf(px2, tx2), rby = fminf(py2, ty2);
                float w = fmaxf(rbx - ltx, 0.f), h = fmaxf(rby - lty, 0.f);
                float inter = w * h;
                float area_p = (px2 - px1) * (py2 - py1);
                iou[b] = inter / (area_p + area_t - inter);
            }
            int bi = (iou[1] > iou[0]) ? 1 : 0;   // argmax: first on ties
            float biou = fmaxf(iou[0], iou[1]);

            float bbx = bxv[bi], bby = byv[bi], bbw = bwv[bi], bbh = bhv[bi], bconf = confv[bi];

            // regression loss (x5 at the end)
            float dx = bbx - tb.x, dy = bby - tb.y;
            float center = dx*dx + dy*dy;
            float sw = sqrtf(fmaxf(bbw, 0.f)) - sqrtf(tb.z);
            float sh = sqrtf(fmaxf(bbh, 0.f)) - sqrtf(tb.w);
            s_reg = center + sw*sw + sh*sh;

            // containment loss
            float dc = bconf - biou;
            s_contain = dc * dc;
        }
    }

    // ---- block reduce: 4 waves x 4 sums
    __shared__ float red[4][4];
    int lane = threadIdx.x & 63, wid = threadIdx.x >> 6;
    s_cls = wave_reduce(s_cls);
    s_noobj = wave_reduce(s_noobj);
    s_contain = wave_reduce(s_contain);
    s_reg = wave_reduce(s_reg);
    if (lane == 0) {
        red[wid][0] = s_cls; red[wid][1] = s_noobj;
        red[wid][2] = s_contain; red[wid][3] = s_reg;
    }
    __syncthreads();
    if (threadIdx.x < 4) {
        float acc = red[0][threadIdx.x] + red[1][threadIdx.x]
                  + red[2][threadIdx.x] + red[3][threadIdx.x];
        partial[(size_t)blockIdx.x * 4 + threadIdx.x] = acc;
    }
}

__global__ void __launch_bounds__(256) yolo_final(
    const float* __restrict__ partial, int nblocks, float* __restrict__ out)
{
    float s0 = 0.f, s1 = 0.f, s2 = 0.f, s3 = 0.f;
    const float4* p4 = (const float4*)partial;
    for (int i = threadIdx.x; i < nblocks; i += 256) {
        float4 t = p4[i];
        s0 += t.x; s1 += t.y; s2 += t.z; s3 += t.w;
    }
    __shared__ float red[4][4];
    int lane = threadIdx.x & 63, wid = threadIdx.x >> 6;
    s0 = wave_reduce(s0); s1 = wave_reduce(s1);
    s2 = wave_reduce(s2); s3 = wave_reduce(s3);
    if (lane == 0) { red[wid][0]=s0; red[wid][1]=s1; red[wid][2]=s2; red[wid][3]=s3; }
    __syncthreads();
    if (threadIdx.x == 0) {
        float cls = 0.f, noobj = 0.f, contain = 0.f, reg = 0.f;
        #pragma unroll
        for (int w = 0; w < 4; w++) {
            cls += red[w][0]; noobj += red[w][1];
            contain += red[w][2]; reg += red[w][3];
        }
        noobj *= 0.5f;   // L_NOOBJ
        reg   *= 5.0f;   // L_COORD
        float total = (cls + noobj + contain + reg) / 1024.0f;
        out[0] = total; out[1] = reg; out[2] = contain;
        out[3] = noobj; out[4] = cls;
    }
}

extern "C" void kernel_launch(void* const* d_in, const int* in_sizes, int n_in,
                              void* d_out, int out_size, void* d_ws, size_t ws_size,
                              hipStream_t stream) {
    const float* pred = (const float*)d_in[0];
    const float* tbox = (const float*)d_in[1];
    const float* tcls = (const float*)d_in[2];
    const int*   mask = (const int*)d_in[3];

    int ncells = in_sizes[3];                 // N * S * S = 802816
    int nblocks = (ncells + 255) / 256;       // 3136
    int maxblocks = (int)(ws_size / (4 * sizeof(float)));
    if (nblocks > maxblocks) nblocks = maxblocks;
    if (nblocks < 1) nblocks = 1;

    yolo_partial<<<nblocks, 256, 0, stream>>>(
        pred, tbox, tcls, mask, (float*)d_ws, ncells);
    yolo_final<<<1, 256, 0, stream>>>((float*)d_ws, nblocks, (float*)d_out);
}